// Round 2
// baseline (38484.891 us; speedup 1.0000x reference)
//
#include <hip/hip_runtime.h>

#define TT 1024
#define BB 256
#define HH 512
#define G4 2048
#define NG 16   // sample groups (barrier groups)
#define SG 16   // samples per group
#define NJ 16   // wgs per group (j-split)
#define RW 128  // rows per wg = 4 gates * 32 j
#define JW 32   // j per wg

// ---------------- prep: weight repack + bias fuse + init ----------------
__global__ __launch_bounds__(256) void prep_k(
    const float* __restrict__ Whh, const float* __restrict__ fcW,
    const float* __restrict__ bih, const float* __restrict__ bhh,
    float* __restrict__ WTg, float* __restrict__ fcWT, float* __restrict__ bsum,
    float* __restrict__ h0, unsigned* __restrict__ bar)
{
    int n  = blockDim.x * gridDim.x;
    int i0 = blockIdx.x * blockDim.x + threadIdx.x;
    // WTg[jg][k][rl] = Whh[gate*512 + jg*32 + jj][k],  rl = gate*32+jj
    for (int i = i0; i < NJ * HH * RW; i += n) {
        int jg = i >> 16, k = (i >> 7) & (HH - 1), rl = i & (RW - 1);
        int gate = rl >> 5, jj = rl & 31;
        int row = gate * HH + jg * JW + jj;
        WTg[i] = Whh[row * HH + k];
    }
    // fcWT[k][t] = fcW[t][k]
    for (int i = i0; i < HH * TT; i += n) {
        int k = i >> 10, t = i & (TT - 1);
        fcWT[i] = fcW[t * HH + k];
    }
    for (int i = i0; i < G4; i += n) bsum[i] = bih[i] + bhh[i];
    for (int i = i0; i < BB * HH; i += n) h0[i] = 0.f;
    for (int i = i0; i < NG * 32; i += n) bar[i] = 0u;
}

// ---------------- lengths ----------------
__global__ __launch_bounds__(256) void lens_k(const float* __restrict__ traj,
                                              int* __restrict__ len)
{
    int b = blockIdx.x;
    int cnt = 0;
    for (int i = threadIdx.x; i < TT; i += 256)
        cnt += (traj[b * TT + i] != -1.0f) ? 1 : 0;
    for (int o = 32; o > 0; o >>= 1) cnt += __shfl_down(cnt, o, 64);
    __shared__ int s4[4];
    if ((threadIdx.x & 63) == 0) s4[threadIdx.x >> 6] = cnt;
    __syncthreads();
    if (threadIdx.x == 0) len[b] = s4[0] + s4[1] + s4[2] + s4[3];
}

// ---------------- sort by length (descending), group maxes ----------------
__global__ __launch_bounds__(256) void sort_k(const int* __restrict__ len,
                                              int* __restrict__ perm,
                                              int* __restrict__ glen)
{
    __shared__ int L[256];
    __shared__ int P[256];
    int tid = threadIdx.x;
    L[tid] = len[tid];
    __syncthreads();
    int l = L[tid], r = 0;
    for (int b = 0; b < 256; ++b) {
        int lb = L[b];
        r += (lb > l) || (lb == l && b < tid);
    }
    P[r] = tid;
    __syncthreads();
    perm[tid] = P[tid];
    if (tid < NG) glen[tid] = L[P[tid * SG]];
}

// ---------------- persistent LSTM ----------------
__global__ __launch_bounds__(512) void lstm_persist(
    const float* __restrict__ traj, const float* __restrict__ Wih,
    const float* __restrict__ WTg, const float* __restrict__ bsum,
    float* __restrict__ h0, float* __restrict__ h1,
    const int* __restrict__ perm, const int* __restrict__ glen,
    unsigned* __restrict__ bar)
{
    __shared__ float hs[HH * 17];      // [k*17 + s]
    __shared__ float gbuf[SG * RW];    // [s*128 + rl]
    __shared__ float xs[SG], msk[SG];
    __shared__ float wih_s[RW], bsum_s[RW];
    __shared__ int os_s[SG];

    const int wg  = blockIdx.x;        // 0..255
    const int bg  = wg & (NG - 1);     // group
    const int jg  = wg >> 4;           // 0..15
    const int tid = threadIdx.x;

    if (tid < SG) os_s[tid] = perm[bg * SG + tid];
    if (tid < RW) {
        int gate = tid >> 5, jj = tid & 31;
        int row = gate * HH + jg * JW + jj;
        wih_s[tid]  = Wih[row];
        bsum_s[tid] = bsum[row];
    }
    const int glenv = glen[bg];
    __syncthreads();

    const int s_mv = tid >> 5;          // 0..15 (sample, matvec role)
    const int cq   = tid & 31;          // col quad
    const int rl0  = cq * 4;
    const float* wbase = WTg + (size_t)jg * HH * RW + rl0;

    const int s_up = tid >> 5;          // update role: same split
    const int j_up = tid & 31;
    float creg = 0.f;

    float* hin  = h0;
    float* hout = h1;
    unsigned* cntp = bar + bg * 32;
    unsigned* genp = bar + bg * 32 + 1;

    for (int t = 0; t < TT; ++t) {
        if (t >= glenv) {
            // whole group done forever: mirror newest slice into other buffer, exit
            int idx = (bg * SG + s_up) * HH + jg * JW + j_up;
            hout[idx] = hin[idx];
            return;
        }
        if (tid < SG) {
            float v = traj[(size_t)os_s[tid] * TT + t];
            xs[tid]  = v;
            msk[tid] = (v != -1.0f) ? 1.f : 0.f;
        }
        // stage group h: coalesced global read, swizzled LDS write (stride 17)
        for (int i = tid; i < HH * SG; i += 512) {
            int s = i >> 9, k = i & (HH - 1);
            hs[k * 17 + s] = hin[(size_t)(bg * SG + s) * HH + k];
        }
        __syncthreads();

        float a0 = 0.f, a1 = 0.f, a2 = 0.f, a3 = 0.f;
        const float* wp = wbase;
        #pragma unroll 8
        for (int k = 0; k < HH; ++k) {
            float4 w = *(const float4*)wp;
            wp += RW;
            float hv = hs[k * 17 + s_mv];
            a0 = fmaf(w.x, hv, a0);
            a1 = fmaf(w.y, hv, a1);
            a2 = fmaf(w.z, hv, a2);
            a3 = fmaf(w.w, hv, a3);
        }
        // gate nonlinearity (branchless tanh-via-sigmoid)
        {
            float accv[4] = {a0, a1, a2, a3};
            float xv = xs[s_mv];
            float4 gout;
            float* go = &gout.x;
            #pragma unroll
            for (int q = 0; q < 4; ++q) {
                int rl = rl0 + q;
                float pre = fmaf(xv, wih_s[rl], accv[q] + bsum_s[rl]);
                bool isg = ((rl >> 5) == 2);
                float sc = isg ? 2.f : 1.f;
                float sg = 1.f / (1.f + __expf(-pre * sc));
                go[q] = fmaf(sg, sc, isg ? -1.f : 0.f);
            }
            *(float4*)&gbuf[s_mv * RW + rl0] = gout;
        }
        __syncthreads();

        // state update (c lives in a register)
        {
            int idx = (bg * SG + s_up) * HH + jg * JW + j_up;
            float hv;
            if (msk[s_up] > 0.f) {
                float iv = gbuf[s_up * RW + j_up];
                float fv = gbuf[s_up * RW + 32 + j_up];
                float gv = gbuf[s_up * RW + 64 + j_up];
                float ov = gbuf[s_up * RW + 96 + j_up];
                float cn = fmaf(fv, creg, iv * gv);
                creg = cn;
                float e  = __expf(2.f * cn);
                float th = 1.f - 2.f / (e + 1.f);
                hv = ov * th;
            } else {
                hv = hs[(jg * JW + j_up) * 17 + s_up];
            }
            hout[idx] = hv;
        }
        __syncthreads();  // all stores issued+drained (vmcnt(0) before s_barrier)

        // per-group inter-wg barrier (sense-reversing, agent scope)
        if (tid == 0) {
            unsigned g = __hip_atomic_load(genp, __ATOMIC_RELAXED, __HIP_MEMORY_SCOPE_AGENT);
            unsigned a = __hip_atomic_fetch_add(cntp, 1u, __ATOMIC_RELEASE, __HIP_MEMORY_SCOPE_AGENT);
            if (a == NJ - 1) {
                __hip_atomic_store(cntp, 0u, __ATOMIC_RELAXED, __HIP_MEMORY_SCOPE_AGENT);
                __hip_atomic_fetch_add(genp, 1u, __ATOMIC_RELEASE, __HIP_MEMORY_SCOPE_AGENT);
            } else {
                while (__hip_atomic_load(genp, __ATOMIC_RELAXED, __HIP_MEMORY_SCOPE_AGENT) == g)
                    __builtin_amdgcn_s_sleep(2);
            }
            __builtin_amdgcn_fence(__ATOMIC_ACQUIRE, "agent");
        }
        __syncthreads();

        float* tmp = hin; hin = hout; hout = tmp;
    }
}

// ---------------- epilogue: logits + masked softmax ----------------
__global__ __launch_bounds__(256) void epi_k(
    const float* __restrict__ hfin, const float* __restrict__ fcWT,
    const float* __restrict__ fcb, const int* __restrict__ len,
    const int* __restrict__ perm, float* __restrict__ out)
{
    __shared__ float hb[HH];
    __shared__ float lg[TT];
    __shared__ float red[4];
    const int slot = blockIdx.x, tid = threadIdx.x;
    const int ob = perm[slot];

    for (int i = tid; i < HH; i += 256) hb[i] = hfin[slot * HH + i];
    __syncthreads();

    const int t0 = tid * 4;
    float a0 = fcb[t0], a1 = fcb[t0 + 1], a2 = fcb[t0 + 2], a3 = fcb[t0 + 3];
    #pragma unroll 8
    for (int k = 0; k < HH; ++k) {
        float4 w = *(const float4*)&fcWT[k * TT + t0];
        float hv = hb[k];
        a0 += w.x * hv; a1 += w.y * hv; a2 += w.z * hv; a3 += w.w * hv;
    }
    lg[t0] = a0; lg[t0 + 1] = a1; lg[t0 + 2] = a2; lg[t0 + 3] = a3;
    __syncthreads();

    const int L = len[ob];
    float mx = -3.4e38f;
    for (int i = tid; i < L; i += 256) mx = fmaxf(mx, lg[i]);
    for (int o = 32; o > 0; o >>= 1) mx = fmaxf(mx, __shfl_down(mx, o, 64));
    if ((tid & 63) == 0) red[tid >> 6] = mx;
    __syncthreads();
    mx = fmaxf(fmaxf(red[0], red[1]), fmaxf(red[2], red[3]));
    __syncthreads();

    float sm = 0.f;
    for (int i = tid; i < L; i += 256) {
        float e = __expf(lg[i] - mx);
        lg[i] = e;
        sm += e;
    }
    for (int o = 32; o > 0; o >>= 1) sm += __shfl_down(sm, o, 64);
    if ((tid & 63) == 0) red[tid >> 6] = sm;
    __syncthreads();
    sm = red[0] + red[1] + red[2] + red[3];
    float inv = 1.f / sm;

    for (int i = tid; i < TT; i += 256)
        out[ob * TT + i] = (i < L) ? lg[i] * inv : 1.0f;
}

// ---------------- launch ----------------
extern "C" void kernel_launch(void* const* d_in, const int* in_sizes, int n_in,
                              void* d_out, int out_size, void* d_ws, size_t ws_size,
                              hipStream_t stream)
{
    const float* traj = (const float*)d_in[0];
    const float* Wih  = (const float*)d_in[1];
    const float* Whh  = (const float*)d_in[2];
    const float* bih  = (const float*)d_in[3];
    const float* bhh  = (const float*)d_in[4];
    const float* fcW  = (const float*)d_in[5];
    const float* fcb  = (const float*)d_in[6];
    float* out = (float*)d_out;

    float* ws   = (float*)d_ws;
    float* WTg  = ws;                        // 1,048,576
    float* fcWT = WTg + NJ * HH * RW;        // 524,288
    float* bsum = fcWT + HH * TT;            // 2,048
    float* h0   = bsum + G4;                 // 131,072
    float* h1   = h0 + BB * HH;              // 131,072
    int*   len  = (int*)(h1 + BB * HH);      // 256
    int*   perm = len + BB;                  // 256
    int*   glen = perm + BB;                 // 16
    unsigned* bar = (unsigned*)(glen + NG);  // 16*32

    prep_k<<<2048, 256, 0, stream>>>(Whh, fcW, bih, bhh, WTg, fcWT, bsum, h0, bar);
    lens_k<<<BB, 256, 0, stream>>>(traj, len);
    sort_k<<<1, 256, 0, stream>>>(len, perm, glen);

    {
        const float* traj_l = traj; const float* wih_l = Wih;
        const float* wtg_l = WTg;   const float* bsum_l = bsum;
        float* h0_l = h0;           float* h1_l = h1;
        const int* perm_l = perm;   const int* glen_l = glen;
        unsigned* bar_l = bar;
        void* args[] = { (void*)&traj_l, (void*)&wih_l, (void*)&wtg_l, (void*)&bsum_l,
                         (void*)&h0_l, (void*)&h1_l, (void*)&perm_l, (void*)&glen_l,
                         (void*)&bar_l };
        hipLaunchCooperativeKernel((const void*)lstm_persist, dim3(256), dim3(512),
                                   args, 0, stream);
    }

    epi_k<<<BB, 256, 0, stream>>>(h0, fcWT, fcb, len, perm, out);
}

// Round 3
// 17690.909 us; speedup vs baseline: 2.1754x; 2.1754x over previous
//
#include <hip/hip_runtime.h>

#define TT 1024
#define BB 256
#define HH 512
#define G4 2048
#define NG 16   // sample groups (barrier groups)
#define SG 16   // samples per group
#define NJ 16   // wgs per group (j-split)
#define RW 128  // rows per wg = 4 gates * 32 j
#define JW 32   // j per wg

// ---------------- prep: weight repack + bias fuse + init ----------------
// Wpk[(jg*512 + tid)*128 + rr*16 + j] = Whh[(gate*512 + jg*32 + jj)*512 + kc*16 + j]
//   where rowq=tid>>5, kc=tid&31, rl=rowq*8+rr, gate=rl>>5, jj=rl&31
__global__ __launch_bounds__(256) void prep_k(
    const float* __restrict__ Whh, const float* __restrict__ fcW,
    const float* __restrict__ bih, const float* __restrict__ bhh,
    float* __restrict__ Wpk, float* __restrict__ fcWT, float* __restrict__ bsum,
    float* __restrict__ h0, unsigned* __restrict__ bar)
{
    int n  = blockDim.x * gridDim.x;
    int i0 = blockIdx.x * blockDim.x + threadIdx.x;
    for (int i = i0; i < NJ * 512 * RW; i += n) {
        int tp   = i >> 7;            // jg*512 + tid
        int inner= i & 127;
        int jg   = tp >> 9;
        int tid  = tp & 511;
        int rowq = tid >> 5, kc = tid & 31;
        int rr   = inner >> 4, j = inner & 15;
        int rl   = rowq * 8 + rr;
        int gate = rl >> 5, jj = rl & 31;
        int grow = gate * HH + jg * JW + jj;
        Wpk[i] = Whh[grow * HH + kc * 16 + j];
    }
    for (int i = i0; i < HH * TT; i += n) {
        int k = i >> 10, t = i & (TT - 1);
        fcWT[i] = fcW[t * HH + k];
    }
    for (int i = i0; i < G4; i += n) bsum[i] = bih[i] + bhh[i];
    for (int i = i0; i < BB * HH; i += n) h0[i] = 0.f;
    for (int i = i0; i < NG * 32; i += n) bar[i] = 0u;
}

// ---------------- lengths ----------------
__global__ __launch_bounds__(256) void lens_k(const float* __restrict__ traj,
                                              int* __restrict__ len)
{
    int b = blockIdx.x;
    int cnt = 0;
    for (int i = threadIdx.x; i < TT; i += 256)
        cnt += (traj[b * TT + i] != -1.0f) ? 1 : 0;
    for (int o = 32; o > 0; o >>= 1) cnt += __shfl_down(cnt, o, 64);
    __shared__ int s4[4];
    if ((threadIdx.x & 63) == 0) s4[threadIdx.x >> 6] = cnt;
    __syncthreads();
    if (threadIdx.x == 0) len[b] = s4[0] + s4[1] + s4[2] + s4[3];
}

// ---------------- sort by length (descending), group maxes ----------------
__global__ __launch_bounds__(256) void sort_k(const int* __restrict__ len,
                                              int* __restrict__ perm,
                                              int* __restrict__ glen)
{
    __shared__ int L[256];
    __shared__ int P[256];
    int tid = threadIdx.x;
    L[tid] = len[tid];
    __syncthreads();
    int l = L[tid], r = 0;
    for (int b = 0; b < 256; ++b) {
        int lb = L[b];
        r += (lb > l) || (lb == l && b < tid);
    }
    P[r] = tid;
    __syncthreads();
    perm[tid] = P[tid];
    if (tid < NG) glen[tid] = L[P[tid * SG]];
}

// ---------------- persistent LSTM, register-resident W ----------------
__global__ __launch_bounds__(512, 2) void lstm_persist(
    const float* __restrict__ traj, const float* __restrict__ Wih,
    const float* __restrict__ Wpk, const float* __restrict__ bsum,
    float* __restrict__ h0, float* __restrict__ h1,
    const int* __restrict__ perm, const int* __restrict__ glen,
    unsigned* __restrict__ bar)
{
    __shared__ float hs[SG * HH];          // swizzled [s][k]
    __shared__ float gbuf[SG * 132];       // [s][row] pad 132
    __shared__ float xs[SG], msk[SG];
    __shared__ float wih_s[RW], bsum_s[RW];
    __shared__ int os_s[SG];

    const int wg  = blockIdx.x;
    const int bg  = wg & (NG - 1);
    const int jg  = wg >> 4;
    const int tid = threadIdx.x;

    const int rowq = tid >> 5;     // 0..15 : owns rows rowq*8..+7
    const int kc   = tid & 31;     // 0..31 : owns k kc*16..+15
    const int swz  = (kc & 7) << 2;

    if (tid < SG) os_s[tid] = perm[bg * SG + tid];
    if (tid < RW) {
        int gate = tid >> 5, jj = tid & 31;
        int grow = gate * HH + jg * JW + jj;
        wih_s[tid]  = Wih[grow];
        bsum_s[tid] = bsum[grow];
    }
    const int glenv = glen[bg];

    // load W block into registers: 32 float4 = 128 floats
    float4 w4[32];
    {
        const float4* wp4 = (const float4*)(Wpk + ((size_t)(jg * 512 + tid)) * 128);
        #pragma unroll
        for (int i = 0; i < 32; ++i) w4[i] = wp4[i];
    }
    __syncthreads();

    const int s_up = tid >> 5;     // update role
    const int j_up = tid & 31;
    float creg = 0.f;

    float* hin  = h0;
    float* hout = h1;
    unsigned* cntp = bar + bg * 32;
    unsigned* genp = bar + bg * 32 + 1;

    for (int t = 0; t < TT; ++t) {
        if (t >= glenv) {
            int idx = (bg * SG + s_up) * HH + jg * JW + j_up;
            hout[idx] = hin[idx];
            return;
        }
        if (tid < SG) {
            float v = traj[(size_t)os_s[tid] * TT + t];
            xs[tid]  = v;
            msk[tid] = (v != -1.0f) ? 1.f : 0.f;
        }
        // stage group h -> LDS (swizzled)
        {
            int s = tid >> 5, kc2 = tid & 31;
            const float4* gp = (const float4*)&hin[(size_t)(bg * SG + s) * HH + kc2 * 16];
            float4 g0 = gp[0], g1 = gp[1], g2 = gp[2], g3 = gp[3];
            int base = (s * 32 + kc2) * 16;
            int sw2  = (kc2 & 7) << 2;
            *(float4*)&hs[(base     ) ^ sw2] = g0;
            *(float4*)&hs[(base +  4) ^ sw2] = g1;
            *(float4*)&hs[(base +  8) ^ sw2] = g2;
            *(float4*)&hs[(base + 12) ^ sw2] = g3;
        }
        __syncthreads();

        // 4 chunks of 4 samples
        #pragma unroll
        for (int cs = 0; cs < 4; ++cs) {
            float a[32];
            #pragma unroll
            for (int i = 0; i < 32; ++i) a[i] = 0.f;
            #pragma unroll
            for (int sp = 0; sp < 4; ++sp) {
                const int s = cs * 4 + sp;
                float4 h4[4];
                const int base = (s * 32 + kc) * 16;
                #pragma unroll
                for (int jq = 0; jq < 4; ++jq)
                    h4[jq] = *(const float4*)&hs[(base + jq * 4) ^ swz];
                #pragma unroll
                for (int rr = 0; rr < 8; ++rr) {
                    float acc = a[sp * 8 + rr];
                    #pragma unroll
                    for (int jq = 0; jq < 4; ++jq) {
                        const float4 w = w4[rr * 4 + jq];
                        acc = fmaf(w.x, h4[jq].x, acc);
                        acc = fmaf(w.y, h4[jq].y, acc);
                        acc = fmaf(w.z, h4[jq].z, acc);
                        acc = fmaf(w.w, h4[jq].w, acc);
                    }
                    a[sp * 8 + rr] = acc;
                }
            }
            // fold-reduce across 32 kc lanes: 32 values -> 1 per lane
            #pragma unroll
            for (int d = 0; d < 5; ++d) {
                const unsigned bsel = (kc >> d) & 1;
                #pragma unroll
                for (int j = 0; j < (16 >> d); ++j) {
                    float v0 = a[2 * j], v1 = a[2 * j + 1];
                    float send = bsel ? v0 : v1;
                    float keep = bsel ? v1 : v0;
                    float r = __shfl_xor(send, 1 << d, 64);
                    a[j] = keep + r;
                }
            }
            // lane kc holds (row = rowq*8 + (kc&7), sample = cs*4 + (kc>>3))
            {
                const int rloc = rowq * 8 + (kc & 7);
                const int sloc = cs * 4 + (kc >> 3);
                float pre = fmaf(xs[sloc], wih_s[rloc], a[0] + bsum_s[rloc]);
                bool isg = ((rloc >> 5) == 2);
                float sc = isg ? 2.f : 1.f;
                float sg = 1.f / (1.f + __expf(-pre * sc));
                gbuf[sloc * 132 + rloc] = fmaf(sg, sc, isg ? -1.f : 0.f);
            }
        }
        __syncthreads();

        // state update (c in register)
        {
            int idx = (bg * SG + s_up) * HH + jg * JW + j_up;
            float hv;
            if (msk[s_up] > 0.f) {
                float iv = gbuf[s_up * 132 + j_up];
                float fv = gbuf[s_up * 132 + 32 + j_up];
                float gv = gbuf[s_up * 132 + 64 + j_up];
                float ov = gbuf[s_up * 132 + 96 + j_up];
                float cn = fmaf(fv, creg, iv * gv);
                creg = cn;
                float e  = __expf(2.f * cn);
                float th = 1.f - 2.f / (e + 1.f);
                hv = ov * th;
            } else {
                int k   = jg * JW + j_up;
                int kc2 = k >> 4;
                int idx2 = ((s_up * 32 + kc2) * 16 + (k & 15)) ^ ((kc2 & 7) << 2);
                hv = hs[idx2];
            }
            hout[idx] = hv;
        }
        __syncthreads();

        // per-group inter-wg barrier (sense-reversing, agent scope)
        if (tid == 0) {
            unsigned g = __hip_atomic_load(genp, __ATOMIC_RELAXED, __HIP_MEMORY_SCOPE_AGENT);
            unsigned a = __hip_atomic_fetch_add(cntp, 1u, __ATOMIC_RELEASE, __HIP_MEMORY_SCOPE_AGENT);
            if (a == NJ - 1) {
                __hip_atomic_store(cntp, 0u, __ATOMIC_RELAXED, __HIP_MEMORY_SCOPE_AGENT);
                __hip_atomic_fetch_add(genp, 1u, __ATOMIC_RELEASE, __HIP_MEMORY_SCOPE_AGENT);
            } else {
                while (__hip_atomic_load(genp, __ATOMIC_RELAXED, __HIP_MEMORY_SCOPE_AGENT) == g)
                    __builtin_amdgcn_s_sleep(2);
            }
            __builtin_amdgcn_fence(__ATOMIC_ACQUIRE, "agent");
        }
        __syncthreads();

        float* tmp = hin; hin = hout; hout = tmp;
    }
}

// ---------------- epilogue: logits + masked softmax ----------------
__global__ __launch_bounds__(256) void epi_k(
    const float* __restrict__ hfin, const float* __restrict__ fcWT,
    const float* __restrict__ fcb, const int* __restrict__ len,
    const int* __restrict__ perm, float* __restrict__ out)
{
    __shared__ float hb[HH];
    __shared__ float lg[TT];
    __shared__ float red[4];
    const int slot = blockIdx.x, tid = threadIdx.x;
    const int ob = perm[slot];

    for (int i = tid; i < HH; i += 256) hb[i] = hfin[slot * HH + i];
    __syncthreads();

    const int t0 = tid * 4;
    float a0 = fcb[t0], a1 = fcb[t0 + 1], a2 = fcb[t0 + 2], a3 = fcb[t0 + 3];
    #pragma unroll 8
    for (int k = 0; k < HH; ++k) {
        float4 w = *(const float4*)&fcWT[k * TT + t0];
        float hv = hb[k];
        a0 += w.x * hv; a1 += w.y * hv; a2 += w.z * hv; a3 += w.w * hv;
    }
    lg[t0] = a0; lg[t0 + 1] = a1; lg[t0 + 2] = a2; lg[t0 + 3] = a3;
    __syncthreads();

    const int L = len[ob];
    float mx = -3.4e38f;
    for (int i = tid; i < L; i += 256) mx = fmaxf(mx, lg[i]);
    for (int o = 32; o > 0; o >>= 1) mx = fmaxf(mx, __shfl_down(mx, o, 64));
    if ((tid & 63) == 0) red[tid >> 6] = mx;
    __syncthreads();
    mx = fmaxf(fmaxf(red[0], red[1]), fmaxf(red[2], red[3]));
    __syncthreads();

    float sm = 0.f;
    for (int i = tid; i < L; i += 256) {
        float e = __expf(lg[i] - mx);
        lg[i] = e;
        sm += e;
    }
    for (int o = 32; o > 0; o >>= 1) sm += __shfl_down(sm, o, 64);
    if ((tid & 63) == 0) red[tid >> 6] = sm;
    __syncthreads();
    sm = red[0] + red[1] + red[2] + red[3];
    float inv = 1.f / sm;

    for (int i = tid; i < TT; i += 256)
        out[ob * TT + i] = (i < L) ? lg[i] * inv : 1.0f;
}

// ---------------- launch ----------------
extern "C" void kernel_launch(void* const* d_in, const int* in_sizes, int n_in,
                              void* d_out, int out_size, void* d_ws, size_t ws_size,
                              hipStream_t stream)
{
    const float* traj = (const float*)d_in[0];
    const float* Wih  = (const float*)d_in[1];
    const float* Whh  = (const float*)d_in[2];
    const float* bih  = (const float*)d_in[3];
    const float* bhh  = (const float*)d_in[4];
    const float* fcW  = (const float*)d_in[5];
    const float* fcb  = (const float*)d_in[6];
    float* out = (float*)d_out;

    float* ws   = (float*)d_ws;
    float* Wpk  = ws;                        // 1,048,576
    float* fcWT = Wpk + NJ * 512 * RW;       // 524,288
    float* bsum = fcWT + HH * TT;            // 2,048
    float* h0   = bsum + G4;                 // 131,072
    float* h1   = h0 + BB * HH;              // 131,072
    int*   len  = (int*)(h1 + BB * HH);      // 256
    int*   perm = len + BB;                  // 256
    int*   glen = perm + BB;                 // 16
    unsigned* bar = (unsigned*)(glen + NG);  // 16*32

    prep_k<<<2048, 256, 0, stream>>>(Whh, fcW, bih, bhh, Wpk, fcWT, bsum, h0, bar);
    lens_k<<<BB, 256, 0, stream>>>(traj, len);
    sort_k<<<1, 256, 0, stream>>>(len, perm, glen);

    {
        const float* traj_l = traj; const float* wih_l = Wih;
        const float* wpk_l = Wpk;   const float* bsum_l = bsum;
        float* h0_l = h0;           float* h1_l = h1;
        const int* perm_l = perm;   const int* glen_l = glen;
        unsigned* bar_l = bar;
        void* args[] = { (void*)&traj_l, (void*)&wih_l, (void*)&wpk_l, (void*)&bsum_l,
                         (void*)&h0_l, (void*)&h1_l, (void*)&perm_l, (void*)&glen_l,
                         (void*)&bar_l };
        hipLaunchCooperativeKernel((const void*)lstm_persist, dim3(256), dim3(512),
                                   args, 0, stream);
    }

    epi_k<<<BB, 256, 0, stream>>>(h0, fcWT, fcb, len, perm, out);
}

// Round 4
// 15680.753 us; speedup vs baseline: 2.4543x; 1.1282x over previous
//
#include <hip/hip_runtime.h>

#define TT 1024
#define BB 256
#define HH 512
#define G4 2048
#define NG 32   // sample groups
#define SG 8    // samples per group
#define NJ 16   // wgs (j-slices) per group
#define NP 16   // group pairs; wg = jg*16 + p serves groups 2p, 2p+1
#define RW 128  // rows per slice = 4 gates * 32 j
#define JW 32   // j per slice
#define FS 32   // flag stride (ints) to avoid false sharing

// ---------------- prep: weight repack + bias fuse + init ----------------
// Wpk[(jg*512 + tid)*128 + rr*16 + j] = Whh[(gate*512 + jg*32 + jj)*512 + kc*16 + j]
//   rowq=tid>>5, kc=tid&31, rl=rowq*8+rr, gate=rl>>5, jj=rl&31
__global__ __launch_bounds__(256) void prep_k(
    const float* __restrict__ Whh, const float* __restrict__ fcW,
    const float* __restrict__ bih, const float* __restrict__ bhh,
    float* __restrict__ Wpk, float* __restrict__ fcWT, float* __restrict__ bsum,
    float* __restrict__ hbuf, int* __restrict__ flags)
{
    int n  = blockDim.x * gridDim.x;
    int i0 = blockIdx.x * blockDim.x + threadIdx.x;
    for (int i = i0; i < NJ * 512 * RW; i += n) {
        int tp   = i >> 7;
        int inner= i & 127;
        int jg   = tp >> 9;
        int tid  = tp & 511;
        int rowq = tid >> 5, kc = tid & 31;
        int rr   = inner >> 4, j = inner & 15;
        int rl   = rowq * 8 + rr;
        int gate = rl >> 5, jj = rl & 31;
        int grow = gate * HH + jg * JW + jj;
        Wpk[i] = Whh[grow * HH + kc * 16 + j];
    }
    for (int i = i0; i < HH * TT; i += n) {
        int k = i >> 10, t = i & (TT - 1);
        fcWT[i] = fcW[t * HH + k];
    }
    for (int i = i0; i < G4; i += n) bsum[i] = bih[i] + bhh[i];
    for (int i = i0; i < 2 * BB * HH; i += n) hbuf[i] = 0.f;
    for (int i = i0; i < NG * NJ * FS; i += n) flags[i] = 0;
}

// ---------------- lengths ----------------
__global__ __launch_bounds__(256) void lens_k(const float* __restrict__ traj,
                                              int* __restrict__ len)
{
    int b = blockIdx.x;
    int cnt = 0;
    for (int i = threadIdx.x; i < TT; i += 256)
        cnt += (traj[b * TT + i] != -1.0f) ? 1 : 0;
    for (int o = 32; o > 0; o >>= 1) cnt += __shfl_down(cnt, o, 64);
    __shared__ int s4[4];
    if ((threadIdx.x & 63) == 0) s4[threadIdx.x >> 6] = cnt;
    __syncthreads();
    if (threadIdx.x == 0) len[b] = s4[0] + s4[1] + s4[2] + s4[3];
}

// ---------------- sort by length (descending), group maxes ----------------
__global__ __launch_bounds__(256) void sort_k(const int* __restrict__ len,
                                              int* __restrict__ perm,
                                              int* __restrict__ glen)
{
    __shared__ int L[256];
    __shared__ int P[256];
    int tid = threadIdx.x;
    L[tid] = len[tid];
    __syncthreads();
    int l = L[tid], r = 0;
    for (int b = 0; b < 256; ++b) {
        int lb = L[b];
        r += (lb > l) || (lb == l && b < tid);
    }
    P[r] = tid;
    __syncthreads();
    perm[tid] = P[tid];
    if (tid < NG) glen[tid] = L[P[tid * SG]];
}

// ---------------- persistent LSTM: reg-W, dual-group pipelined ----------------
__global__ __launch_bounds__(512, 2) void lstm_persist(
    const float* __restrict__ traj, const float* __restrict__ Wih,
    const float* __restrict__ Wpk, const float* __restrict__ bsum,
    float* __restrict__ hbuf,                 // [2][BB][HH]
    const int* __restrict__ perm, const int* __restrict__ glen,
    int* __restrict__ flags)
{
    __shared__ __align__(16) float hs[2][SG * HH];   // swizzled [s][k]
    __shared__ float gbuf[2][SG * 136];
    __shared__ float xs[2][SG], msk[2][SG];
    __shared__ int   os_s[2][SG];
    __shared__ float wih_s[RW], bsum_s[RW];
    __shared__ float ldspad[10240];                  // forces 1 wg/CU (>80KB total)

    const int wg  = blockIdx.x;
    const int p   = wg & 15;
    const int jg  = wg >> 4;       // wg = jg*16 + p  -> cohort of a group shares p (same XCD under %8)
    const int tid = threadIdx.x;
    const int gA = 2 * p, gB = 2 * p + 1;

    if (tid < 16) os_s[tid >> 3][tid & 7] = perm[(2 * p + (tid >> 3)) * SG + (tid & 7)];
    if (tid < RW) {
        int gate = tid >> 5, jj = tid & 31;
        int grow = gate * HH + jg * JW + jj;
        wih_s[tid]  = Wih[grow];
        bsum_s[tid] = bsum[grow];
    }
    const int glenA = glen[gA], glenB = glen[gB];   // glenA >= glenB (sorted desc)
    if (glenA < 0) ldspad[tid] = 0.f;               // never true; keeps pad allocated

    // W block -> registers, pinned against rematerialization
    float4 w4[32];
    {
        const float4* wp4 = (const float4*)(Wpk + (size_t)(jg * 512 + tid) * 128);
        #pragma unroll
        for (int i = 0; i < 32; ++i) w4[i] = wp4[i];
        #pragma unroll
        for (int i = 0; i < 32; ++i)
            asm volatile("" : "+v"(w4[i].x), "+v"(w4[i].y), "+v"(w4[i].z), "+v"(w4[i].w));
    }

    const int rowq = tid >> 5, kc = tid & 31;
    const int swz  = (kc & 7) << 2;
    float cA = 0.f, cB = 0.f;
    __syncthreads();

    auto phase = [&](int g, int gi, int t, float& creg) {
        int* flg = flags + g * NJ * FS;
        // wait: cohort finished step t-1 (h[t] visible). Overlapped with other group's phase.
        if (t > 0 && tid < 64) {
            while (true) {
                int v = (tid < NJ)
                    ? __hip_atomic_load(&flg[tid * FS], __ATOMIC_RELAXED, __HIP_MEMORY_SCOPE_AGENT)
                    : t;
                if (__all(v >= t)) break;
                __builtin_amdgcn_s_sleep(1);
            }
        }
        __syncthreads();
        if (tid < SG) {
            float v = traj[(size_t)os_s[gi][tid] * TT + t];
            xs[gi][tid]  = v;
            msk[gi][tid] = (v != -1.0f) ? 1.f : 0.f;
        }
        // stage h[t] (LLC-coherent loads), swizzled LDS
        {
            const float* hin = hbuf + ((size_t)(t & 1) * BB + g * SG) * HH;
            int s = tid >> 6, l = tid & 63;
            #pragma unroll
            for (int q = 0; q < 8; ++q) {
                int k = q * 64 + l;
                float v = __hip_atomic_load(&hin[s * HH + k], __ATOMIC_RELAXED,
                                            __HIP_MEMORY_SCOPE_AGENT);
                int kcell = k >> 4;
                int a4 = ((s * 32 + kcell) * 16 + (k & 12)) ^ ((kcell & 7) << 2);
                hs[gi][a4 + (k & 3)] = v;
            }
        }
        __syncthreads();

        // matvec: 2 chunks of 4 samples
        #pragma unroll
        for (int cs = 0; cs < 2; ++cs) {
            float a[32];
            #pragma unroll
            for (int i = 0; i < 32; ++i) a[i] = 0.f;
            #pragma unroll
            for (int sp = 0; sp < 4; ++sp) {
                const int s = cs * 4 + sp;
                float4 h4[4];
                const int base = (s * 32 + kc) * 16;
                #pragma unroll
                for (int jq = 0; jq < 4; ++jq)
                    h4[jq] = *(const float4*)&hs[gi][(base + jq * 4) ^ swz];
                #pragma unroll
                for (int rr = 0; rr < 8; ++rr) {
                    float acc = a[sp * 8 + rr];
                    #pragma unroll
                    for (int jq = 0; jq < 4; ++jq) {
                        const float4 w = w4[rr * 4 + jq];
                        acc = fmaf(w.x, h4[jq].x, acc);
                        acc = fmaf(w.y, h4[jq].y, acc);
                        acc = fmaf(w.z, h4[jq].z, acc);
                        acc = fmaf(w.w, h4[jq].w, acc);
                    }
                    a[sp * 8 + rr] = acc;
                }
            }
            #pragma unroll
            for (int d = 0; d < 5; ++d) {
                const unsigned bsel = (kc >> d) & 1;
                #pragma unroll
                for (int j = 0; j < (16 >> d); ++j) {
                    float v0 = a[2 * j], v1 = a[2 * j + 1];
                    float send = bsel ? v0 : v1;
                    float keep = bsel ? v1 : v0;
                    float r = __shfl_xor(send, 1 << d, 64);
                    a[j] = keep + r;
                }
            }
            {
                const int rloc = rowq * 8 + (kc & 7);
                const int sloc = cs * 4 + (kc >> 3);
                float pre = fmaf(xs[gi][sloc], wih_s[rloc], a[0] + bsum_s[rloc]);
                bool isg = ((rloc >> 5) == 2);
                float sc = isg ? 2.f : 1.f;
                float sg = 1.f / (1.f + __expf(-pre * sc));
                gbuf[gi][sloc * 136 + rloc] = fmaf(sg, sc, isg ? -1.f : 0.f);
            }
        }
        __syncthreads();

        // state update (c in register), store h[t+1] LLC-coherent
        if (tid < 256) {
            int s = tid >> 5, jj = tid & 31;
            float hv;
            if (msk[gi][s] > 0.f) {
                float iv = gbuf[gi][s * 136 + jj];
                float fv = gbuf[gi][s * 136 + 32 + jj];
                float gv = gbuf[gi][s * 136 + 64 + jj];
                float ov = gbuf[gi][s * 136 + 96 + jj];
                float cn = fmaf(fv, creg, iv * gv);
                creg = cn;
                float e = __expf(2.f * cn);
                hv = ov * (1.f - 2.f / (e + 1.f));
            } else {
                int k = jg * JW + jj;
                int kcell = k >> 4;
                int a4 = ((s * 32 + kcell) * 16 + (k & 12)) ^ ((kcell & 7) << 2);
                hv = hs[gi][a4 + (k & 3)];
            }
            float* hout = hbuf + ((size_t)((t + 1) & 1) * BB + g * SG) * HH;
            __hip_atomic_store(&hout[s * HH + jg * JW + jj], hv, __ATOMIC_RELAXED,
                               __HIP_MEMORY_SCOPE_AGENT);
        }
        __syncthreads();   // drains vmcnt -> all h stores complete before flag
        if (tid == 0)
            __hip_atomic_store(&flg[jg * FS], t + 1, __ATOMIC_RELAXED,
                               __HIP_MEMORY_SCOPE_AGENT);
    };

    for (int t = 0; t < glenA; ++t) {
        phase(gA, 0, t, cA);
        if (t < glenB) phase(gB, 1, t, cB);
    }
}

// ---------------- epilogue: logits + masked softmax ----------------
__global__ __launch_bounds__(256) void epi_k(
    const float* __restrict__ hbuf, const float* __restrict__ fcWT,
    const float* __restrict__ fcb, const int* __restrict__ len,
    const int* __restrict__ perm, const int* __restrict__ glen,
    float* __restrict__ out)
{
    __shared__ float hb[HH];
    __shared__ float lg[TT];
    __shared__ float red[4];
    const int slot = blockIdx.x, tid = threadIdx.x;
    const int ob = perm[slot];
    const int par = glen[slot >> 3] & 1;   // final state parity for this slot's group

    const float* hfin = hbuf + ((size_t)par * BB + slot) * HH;
    for (int i = tid; i < HH; i += 256) hb[i] = hfin[i];
    __syncthreads();

    const int t0 = tid * 4;
    float a0 = fcb[t0], a1 = fcb[t0 + 1], a2 = fcb[t0 + 2], a3 = fcb[t0 + 3];
    #pragma unroll 8
    for (int k = 0; k < HH; ++k) {
        float4 w = *(const float4*)&fcWT[k * TT + t0];
        float hv = hb[k];
        a0 += w.x * hv; a1 += w.y * hv; a2 += w.z * hv; a3 += w.w * hv;
    }
    lg[t0] = a0; lg[t0 + 1] = a1; lg[t0 + 2] = a2; lg[t0 + 3] = a3;
    __syncthreads();

    const int L = len[ob];
    float mx = -3.4e38f;
    for (int i = tid; i < L; i += 256) mx = fmaxf(mx, lg[i]);
    for (int o = 32; o > 0; o >>= 1) mx = fmaxf(mx, __shfl_down(mx, o, 64));
    if ((tid & 63) == 0) red[tid >> 6] = mx;
    __syncthreads();
    mx = fmaxf(fmaxf(red[0], red[1]), fmaxf(red[2], red[3]));
    __syncthreads();

    float sm = 0.f;
    for (int i = tid; i < L; i += 256) {
        float e = __expf(lg[i] - mx);
        lg[i] = e;
        sm += e;
    }
    for (int o = 32; o > 0; o >>= 1) sm += __shfl_down(sm, o, 64);
    if ((tid & 63) == 0) red[tid >> 6] = sm;
    __syncthreads();
    sm = red[0] + red[1] + red[2] + red[3];
    float inv = 1.f / sm;

    for (int i = tid; i < TT; i += 256)
        out[ob * TT + i] = (i < L) ? lg[i] * inv : 1.0f;
}

// ---------------- launch ----------------
extern "C" void kernel_launch(void* const* d_in, const int* in_sizes, int n_in,
                              void* d_out, int out_size, void* d_ws, size_t ws_size,
                              hipStream_t stream)
{
    const float* traj = (const float*)d_in[0];
    const float* Wih  = (const float*)d_in[1];
    const float* Whh  = (const float*)d_in[2];
    const float* bih  = (const float*)d_in[3];
    const float* bhh  = (const float*)d_in[4];
    const float* fcW  = (const float*)d_in[5];
    const float* fcb  = (const float*)d_in[6];
    float* out = (float*)d_out;

    float* ws    = (float*)d_ws;
    float* Wpk   = ws;                         // 1,048,576
    float* fcWT  = Wpk + NJ * 512 * RW;        // 524,288
    float* bsum  = fcWT + HH * TT;             // 2,048
    float* hbuf  = bsum + G4;                  // 2 * 131,072
    int*   len   = (int*)(hbuf + 2 * BB * HH); // 256
    int*   perm  = len + BB;                   // 256
    int*   glen  = perm + BB;                  // 32
    int*   flags = glen + NG;                  // 32*16*32 = 16384

    prep_k<<<2048, 256, 0, stream>>>(Whh, fcW, bih, bhh, Wpk, fcWT, bsum, hbuf, flags);
    lens_k<<<BB, 256, 0, stream>>>(traj, len);
    sort_k<<<1, 256, 0, stream>>>(len, perm, glen);

    {
        const float* traj_l = traj; const float* wih_l = Wih;
        const float* wpk_l = Wpk;   const float* bsum_l = bsum;
        float* hbuf_l = hbuf;
        const int* perm_l = perm;   const int* glen_l = glen;
        int* flags_l = flags;
        void* args[] = { (void*)&traj_l, (void*)&wih_l, (void*)&wpk_l, (void*)&bsum_l,
                         (void*)&hbuf_l, (void*)&perm_l, (void*)&glen_l, (void*)&flags_l };
        hipLaunchCooperativeKernel((const void*)lstm_persist, dim3(256), dim3(512),
                                   args, 0, stream);
    }

    epi_k<<<BB, 256, 0, stream>>>(hbuf, fcWT, fcb, len, perm, glen, out);
}

// Round 5
// 7249.406 us; speedup vs baseline: 5.3087x; 2.1630x over previous
//
#include <hip/hip_runtime.h>

#define TT 1024
#define BB 256
#define HH 512
#define G4 2048
#define NG 32   // sample groups
#define SG 8    // samples per group
#define NJ 16   // wgs (j-slices) per group
#define RW 128  // rows per slice = 4 gates * 32 j
#define JW 32   // j per slice
#define FS 32   // flag stride (ints)

// ---------------- prep: weight repack + bias fuse + init ----------------
// Wpk[(jg*512 + tid)*128 + rr*16 + j] = Whh[(gate*512 + jg*32 + jj)*512 + kc*16 + j]
//   rowq=tid>>5, kc=tid&31, rl=rowq*8+rr, gate=rl>>5, jj=rl&31
__global__ __launch_bounds__(256) void prep_k(
    const float* __restrict__ Whh, const float* __restrict__ fcW,
    const float* __restrict__ bih, const float* __restrict__ bhh,
    float* __restrict__ Wpk, float* __restrict__ fcWT, float* __restrict__ bsum,
    float* __restrict__ hbuf, int* __restrict__ flags)
{
    int n  = blockDim.x * gridDim.x;
    int i0 = blockIdx.x * blockDim.x + threadIdx.x;
    for (int i = i0; i < NJ * 512 * RW; i += n) {
        int tp   = i >> 7;
        int inner= i & 127;
        int jg   = tp >> 9;
        int tid  = tp & 511;
        int rowq = tid >> 5, kc = tid & 31;
        int rr   = inner >> 4, j = inner & 15;
        int rl   = rowq * 8 + rr;
        int gate = rl >> 5, jj = rl & 31;
        int grow = gate * HH + jg * JW + jj;
        Wpk[i] = Whh[grow * HH + kc * 16 + j];
    }
    for (int i = i0; i < HH * TT; i += n) {
        int k = i >> 10, t = i & (TT - 1);
        fcWT[i] = fcW[t * HH + k];
    }
    for (int i = i0; i < G4; i += n) bsum[i] = bih[i] + bhh[i];
    for (int i = i0; i < 2 * BB * HH; i += n) hbuf[i] = 0.f;
    for (int i = i0; i < NG * NJ * FS; i += n) flags[i] = 0;
}

// ---------------- lengths ----------------
__global__ __launch_bounds__(256) void lens_k(const float* __restrict__ traj,
                                              int* __restrict__ len)
{
    int b = blockIdx.x;
    int cnt = 0;
    for (int i = threadIdx.x; i < TT; i += 256)
        cnt += (traj[b * TT + i] != -1.0f) ? 1 : 0;
    for (int o = 32; o > 0; o >>= 1) cnt += __shfl_down(cnt, o, 64);
    __shared__ int s4[4];
    if ((threadIdx.x & 63) == 0) s4[threadIdx.x >> 6] = cnt;
    __syncthreads();
    if (threadIdx.x == 0) len[b] = s4[0] + s4[1] + s4[2] + s4[3];
}

// ---------------- sort by length (descending), group maxes ----------------
__global__ __launch_bounds__(256) void sort_k(const int* __restrict__ len,
                                              int* __restrict__ perm,
                                              int* __restrict__ glen)
{
    __shared__ int L[256];
    __shared__ int P[256];
    int tid = threadIdx.x;
    L[tid] = len[tid];
    __syncthreads();
    int l = L[tid], r = 0;
    for (int b = 0; b < 256; ++b) {
        int lb = L[b];
        r += (lb > l) || (lb == l && b < tid);
    }
    P[r] = tid;
    __syncthreads();
    perm[tid] = P[tid];
    if (tid < NG) glen[tid] = L[P[tid * SG]];
}

// ---------------- helpers ----------------
__device__ __forceinline__ void wait_flags(const int* __restrict__ flg, int target, int tid)
{
    int lane = tid & 63;
    while (true) {
        int v = target;
        if (lane < NJ)
            v = __hip_atomic_load(&flg[lane * FS], __ATOMIC_RELAXED, __HIP_MEMORY_SCOPE_AGENT);
        if (__all(v >= target)) break;
        __builtin_amdgcn_s_sleep(1);
    }
}

__device__ __forceinline__ void issue_pf(const float* __restrict__ hbuf, int g, int T,
                                         float (&pf)[8], int tid)
{
    const float* hsrc = hbuf + ((size_t)(T & 1) * BB + g * SG) * HH;
    int s = tid >> 6, l = tid & 63;
    #pragma unroll
    for (int q = 0; q < 8; ++q)
        pf[q] = __hip_atomic_load(&hsrc[s * HH + q * 64 + l], __ATOMIC_RELAXED,
                                  __HIP_MEMORY_SCOPE_AGENT);
}

// One LSTM step for one group slice.  pfCur holds h(t); prefetches pfN per pfMode:
// pfMode 1: mid-phase (overlaps update/store/flag), pfMode 2: post-flag (solo tail).
__device__ __forceinline__ void do_phase(
    int g, int t, int tid, int jg,
    const float* __restrict__ traj, const int* __restrict__ osL,
    float* __restrict__ hsL, float* __restrict__ gbL,
    float* __restrict__ xsL, float* __restrict__ mkL,
    const float* __restrict__ wih_s, const float* __restrict__ bsum_s,
    const float4 (&w4)[32], float& creg,
    float (&pfCur)[8], float (&pfN)[8], int pfGrp, int pfT, int pfMode,
    float* __restrict__ hbuf, int* __restrict__ flags)
{
    const int rowq = tid >> 5, kc = tid & 31;
    const int swz  = (kc & 7) << 2;

    // stage h(t): regs -> swizzled LDS
    {
        int s = tid >> 6, l = tid & 63;
        #pragma unroll
        for (int q = 0; q < 8; ++q) {
            int k = q * 64 + l;
            int cell = k >> 4;
            int a4 = ((s * 32 + cell) * 16 + (k & 12)) ^ ((cell & 7) << 2);
            hsL[a4 + (k & 3)] = pfCur[q];
        }
    }
    if (tid < SG) {
        float v = traj[(size_t)osL[tid] * TT + t];
        xsL[tid] = v;
        mkL[tid] = (v != -1.0f) ? 1.f : 0.f;
    }
    __syncthreads();

    // matvec: 2 chunks of 4 samples
    #pragma unroll
    for (int cs = 0; cs < 2; ++cs) {
        float a[32];
        #pragma unroll
        for (int i = 0; i < 32; ++i) a[i] = 0.f;
        #pragma unroll
        for (int sp = 0; sp < 4; ++sp) {
            const int s = cs * 4 + sp;
            float4 h4[4];
            const int base = (s * 32 + kc) * 16;
            #pragma unroll
            for (int jq = 0; jq < 4; ++jq)
                h4[jq] = *(const float4*)&hsL[(base + jq * 4) ^ swz];
            #pragma unroll
            for (int rr = 0; rr < 8; ++rr) {
                float acc = a[sp * 8 + rr];
                #pragma unroll
                for (int jq = 0; jq < 4; ++jq) {
                    const float4 w = w4[rr * 4 + jq];
                    acc = fmaf(w.x, h4[jq].x, acc);
                    acc = fmaf(w.y, h4[jq].y, acc);
                    acc = fmaf(w.z, h4[jq].z, acc);
                    acc = fmaf(w.w, h4[jq].w, acc);
                }
                a[sp * 8 + rr] = acc;
            }
        }
        #pragma unroll
        for (int d = 0; d < 5; ++d) {
            const unsigned bsel = (kc >> d) & 1;
            #pragma unroll
            for (int j = 0; j < (16 >> d); ++j) {
                float v0 = a[2 * j], v1 = a[2 * j + 1];
                float send = bsel ? v0 : v1;
                float keep = bsel ? v1 : v0;
                float r = __shfl_xor(send, 1 << d, 64);
                a[j] = keep + r;
            }
        }
        {
            const int rloc = rowq * 8 + (kc & 7);
            const int sloc = cs * 4 + (kc >> 3);
            float pre = fmaf(xsL[sloc], wih_s[rloc], a[0] + bsum_s[rloc]);
            bool isg = ((rloc >> 5) == 2);
            float sc = isg ? 2.f : 1.f;
            float sg = 1.f / (1.f + __expf(-pre * sc));
            gbL[sloc * 136 + rloc] = fmaf(sg, sc, isg ? -1.f : 0.f);
        }
    }

    // mid-phase prefetch: hides LLC latency under update/store/flag/next staging
    if (pfMode == 1) {
        wait_flags(flags + pfGrp * NJ * FS, pfT, tid);
        issue_pf(hbuf, pfGrp, pfT, pfN, tid);
    }
    __syncthreads();

    // state update (c in register), store h(t+1) LLC-coherent
    if (tid < 256) {
        int s = tid >> 5, jj = tid & 31;
        float hv;
        if (mkL[s] > 0.f) {
            float iv = gbL[s * 136 + jj];
            float fv = gbL[s * 136 + 32 + jj];
            float gv = gbL[s * 136 + 64 + jj];
            float ov = gbL[s * 136 + 96 + jj];
            float cn = fmaf(fv, creg, iv * gv);
            creg = cn;
            float e = __expf(2.f * cn);
            hv = ov * (1.f - 2.f / (e + 1.f));
        } else {
            int k = jg * JW + jj;
            int cell = k >> 4;
            int a4 = ((s * 32 + cell) * 16 + (k & 12)) ^ ((cell & 7) << 2);
            hv = hsL[a4 + (k & 3)];
        }
        float* hout = hbuf + ((size_t)((t + 1) & 1) * BB + g * SG) * HH;
        __hip_atomic_store(&hout[s * HH + jg * JW + jj], hv, __ATOMIC_RELAXED,
                           __HIP_MEMORY_SCOPE_AGENT);
    }
    __syncthreads();   // drains vmcnt: h stores visible before flag
    if (tid == 0)
        __hip_atomic_store(&flags[g * NJ * FS + jg * FS], t + 1, __ATOMIC_RELAXED,
                           __HIP_MEMORY_SCOPE_AGENT);
    if (pfMode == 2) {
        wait_flags(flags + pfGrp * NJ * FS, pfT, tid);
        issue_pf(hbuf, pfGrp, pfT, pfN, tid);
    }
}

// ---------------- persistent LSTM: reg-W, balanced pairs, pipelined exchange ----
__global__ __launch_bounds__(512, 2) void lstm_persist(
    const float* __restrict__ traj, const float* __restrict__ Wih,
    const float* __restrict__ Wpk, const float* __restrict__ bsum,
    float* __restrict__ hbuf,                 // [2][BB][HH]
    const int* __restrict__ perm, const int* __restrict__ glen,
    int* __restrict__ flags)
{
    // 92KB genuinely-used static LDS -> exactly 1 wg/CU (no co-residency jitter)
    __shared__ __align__(16) float smem[23040];
    __shared__ float xsm[2][SG], mkm[2][SG];
    __shared__ int   osm[2][SG];
    __shared__ float wih_s[RW], bsum_s[RW];

    float* const hsA = smem;            // 4096
    float* const hsB = smem + 4096;     // 4096
    float* const gbA = smem + 20864;    // 1088 (tops out the 23040 allocation)
    float* const gbB = smem + 21952;    // 1088

    const int wg  = blockIdx.x;
    const int p   = wg & 15;
    const int jg  = wg >> 4;
    const int tid = threadIdx.x;
    const int gA = p, gB = 31 - p;      // balanced pairing: glen[p] + glen[31-p] ~ const

    if (tid < 2 * SG) {
        int gi = tid >> 3, s = tid & 7;
        osm[gi][s] = perm[((gi == 0) ? gA : gB) * SG + s];
    }
    if (tid < RW) {
        int gate = tid >> 5, jj = tid & 31;
        int grow = gate * HH + jg * JW + jj;
        wih_s[tid]  = Wih[grow];
        bsum_s[tid] = bsum[grow];
    }
    const int glenA = glen[gA], glenB = glen[gB];   // glenA >= glenB

    // W slice -> registers (unified VGPR/AGPR file)
    float4 w4[32];
    {
        const float4* wp4 = (const float4*)(Wpk + (size_t)(jg * 512 + tid) * 128);
        #pragma unroll
        for (int i = 0; i < 32; ++i) w4[i] = wp4[i];
    }

    float cA = 0.f, cB = 0.f;
    float pfA[8], pfB[8];
    #pragma unroll
    for (int q = 0; q < 8; ++q) { pfA[q] = 0.f; pfB[q] = 0.f; }   // h(0) = 0
    __syncthreads();

    for (int t = 0; t < glenA; ++t) {
        if (t < glenB) {
            // A phase: mid-prefetch B h(t) (B flags >= t set since last step)
            do_phase(gA, t, tid, jg, traj, osm[0], hsA, gbA, xsm[0], mkm[0],
                     wih_s, bsum_s, w4, cA, pfA, pfB, gB, t, 1, hbuf, flags);
            // B phase: mid-prefetch A h(t+1) (cohort sets A flags ~now)
            do_phase(gB, t, tid, jg, traj, osm[1], hsB, gbB, xsm[1], mkm[1],
                     wih_s, bsum_s, w4, cB, pfB, pfA, gA, t + 1, 1, hbuf, flags);
        } else {
            // solo A: post-flag prefetch of A h(t+1)
            do_phase(gA, t, tid, jg, traj, osm[0], hsA, gbA, xsm[0], mkm[0],
                     wih_s, bsum_s, w4, cA, pfA, pfA, gA, t + 1,
                     (t + 1 < glenA) ? 2 : 0, hbuf, flags);
        }
    }
}

// ---------------- epilogue: logits + masked softmax ----------------
__global__ __launch_bounds__(256) void epi_k(
    const float* __restrict__ hbuf, const float* __restrict__ fcWT,
    const float* __restrict__ fcb, const int* __restrict__ len,
    const int* __restrict__ perm, const int* __restrict__ glen,
    float* __restrict__ out)
{
    __shared__ float hb[HH];
    __shared__ float lg[TT];
    __shared__ float red[4];
    const int slot = blockIdx.x, tid = threadIdx.x;
    const int ob = perm[slot];
    const int par = glen[slot >> 3] & 1;

    const float* hfin = hbuf + ((size_t)par * BB + slot) * HH;
    for (int i = tid; i < HH; i += 256) hb[i] = hfin[i];
    __syncthreads();

    const int t0 = tid * 4;
    float a0 = fcb[t0], a1 = fcb[t0 + 1], a2 = fcb[t0 + 2], a3 = fcb[t0 + 3];
    #pragma unroll 8
    for (int k = 0; k < HH; ++k) {
        float4 w = *(const float4*)&fcWT[k * TT + t0];
        float hv = hb[k];
        a0 += w.x * hv; a1 += w.y * hv; a2 += w.z * hv; a3 += w.w * hv;
    }
    lg[t0] = a0; lg[t0 + 1] = a1; lg[t0 + 2] = a2; lg[t0 + 3] = a3;
    __syncthreads();

    const int L = len[ob];
    float mx = -3.4e38f;
    for (int i = tid; i < L; i += 256) mx = fmaxf(mx, lg[i]);
    for (int o = 32; o > 0; o >>= 1) mx = fmaxf(mx, __shfl_down(mx, o, 64));
    if ((tid & 63) == 0) red[tid >> 6] = mx;
    __syncthreads();
    mx = fmaxf(fmaxf(red[0], red[1]), fmaxf(red[2], red[3]));
    __syncthreads();

    float sm = 0.f;
    for (int i = tid; i < L; i += 256) {
        float e = __expf(lg[i] - mx);
        lg[i] = e;
        sm += e;
    }
    for (int o = 32; o > 0; o >>= 1) sm += __shfl_down(sm, o, 64);
    if ((tid & 63) == 0) red[tid >> 6] = sm;
    __syncthreads();
    sm = red[0] + red[1] + red[2] + red[3];
    float inv = 1.f / sm;

    for (int i = tid; i < TT; i += 256)
        out[ob * TT + i] = (i < L) ? lg[i] * inv : 1.0f;
}

// ---------------- launch ----------------
extern "C" void kernel_launch(void* const* d_in, const int* in_sizes, int n_in,
                              void* d_out, int out_size, void* d_ws, size_t ws_size,
                              hipStream_t stream)
{
    const float* traj = (const float*)d_in[0];
    const float* Wih  = (const float*)d_in[1];
    const float* Whh  = (const float*)d_in[2];
    const float* bih  = (const float*)d_in[3];
    const float* bhh  = (const float*)d_in[4];
    const float* fcW  = (const float*)d_in[5];
    const float* fcb  = (const float*)d_in[6];
    float* out = (float*)d_out;

    float* ws    = (float*)d_ws;
    float* Wpk   = ws;                         // 1,048,576
    float* fcWT  = Wpk + NJ * 512 * RW;        // 524,288
    float* bsum  = fcWT + HH * TT;             // 2,048
    float* hbuf  = bsum + G4;                  // 2 * 131,072
    int*   len   = (int*)(hbuf + 2 * BB * HH); // 256
    int*   perm  = len + BB;                   // 256
    int*   glen  = perm + BB;                  // 32
    int*   flags = glen + NG;                  // 32*16*32

    prep_k<<<2048, 256, 0, stream>>>(Whh, fcW, bih, bhh, Wpk, fcWT, bsum, hbuf, flags);
    lens_k<<<BB, 256, 0, stream>>>(traj, len);
    sort_k<<<1, 256, 0, stream>>>(len, perm, glen);

    {
        const float* traj_l = traj; const float* wih_l = Wih;
        const float* wpk_l = Wpk;   const float* bsum_l = bsum;
        float* hbuf_l = hbuf;
        const int* perm_l = perm;   const int* glen_l = glen;
        int* flags_l = flags;
        void* args[] = { (void*)&traj_l, (void*)&wih_l, (void*)&wpk_l, (void*)&bsum_l,
                         (void*)&hbuf_l, (void*)&perm_l, (void*)&glen_l, (void*)&flags_l };
        hipLaunchCooperativeKernel((const void*)lstm_persist, dim3(256), dim3(512),
                                   args, 0, stream);
    }

    epi_k<<<BB, 256, 0, stream>>>(hbuf, fcWT, fcb, len, perm, glen, out);
}

// Round 6
// 5726.613 us; speedup vs baseline: 6.7204x; 1.2659x over previous
//
#include <hip/hip_runtime.h>

#define TT 1024
#define BB 256
#define HH 512
#define G4 2048
#define NG 32   // sample groups
#define SG 8    // samples per group
#define NJ 16   // wgs (j-slices) per group
#define RW 128  // rows per slice = 4 gates * 32 j
#define JW 32   // j per slice
#define FS 32   // flag stride (ints)

typedef _Float16 half2v __attribute__((ext_vector_type(2)));
typedef unsigned int uint;

union U32H { uint u; half2v h; };
union U64F { unsigned long long u; float f[2]; };

__device__ __forceinline__ half2v puh(uint u) { U32H x; x.u = u; return x.h; }
__device__ __forceinline__ uint pun(half2v h) { U32H x; x.h = h; return x.u; }

// ---------------- prep: fp16 weight repack + bias fuse + init ----------------
// Wpk16[(jg*512 + tid)*64 + rr*8 + u] = pack(Whh[grow][kc*16+2u], Whh[grow][kc*16+2u+1])
//   rowq=tid>>5, kc=tid&31, rl=rowq*8+rr, gate=rl>>5, jj=rl&31, grow=gate*512+jg*32+jj
__global__ __launch_bounds__(256) void prep_k(
    const float* __restrict__ Whh, const float* __restrict__ fcW,
    const float* __restrict__ bih, const float* __restrict__ bhh,
    uint* __restrict__ Wpk16, float* __restrict__ fcWT, float* __restrict__ bsum,
    float* __restrict__ hbuf, int* __restrict__ flags)
{
    int n  = blockDim.x * gridDim.x;
    int i0 = blockIdx.x * blockDim.x + threadIdx.x;
    for (int i = i0; i < NJ * 512 * 64; i += n) {
        int tp    = i >> 6;            // jg*512 + tid
        int inner = i & 63;
        int jg    = tp >> 9;
        int tid   = tp & 511;
        int rowq  = tid >> 5, kc = tid & 31;
        int rr    = inner >> 3, u = inner & 7;
        int rl    = rowq * 8 + rr;
        int gate  = rl >> 5, jj = rl & 31;
        int grow  = gate * HH + jg * JW + jj;
        int k0    = kc * 16 + 2 * u;
        half2v p;
        p.x = (_Float16)Whh[grow * HH + k0];
        p.y = (_Float16)Whh[grow * HH + k0 + 1];
        Wpk16[i] = pun(p);
    }
    for (int i = i0; i < HH * TT; i += n) {
        int k = i >> 10, t = i & (TT - 1);
        fcWT[i] = fcW[t * HH + k];
    }
    for (int i = i0; i < G4; i += n) bsum[i] = bih[i] + bhh[i];
    for (int i = i0; i < 2 * BB * HH; i += n) hbuf[i] = 0.f;
    for (int i = i0; i < NG * NJ * FS; i += n) flags[i] = 0;
}

// ---------------- lengths ----------------
__global__ __launch_bounds__(256) void lens_k(const float* __restrict__ traj,
                                              int* __restrict__ len)
{
    int b = blockIdx.x;
    int cnt = 0;
    for (int i = threadIdx.x; i < TT; i += 256)
        cnt += (traj[b * TT + i] != -1.0f) ? 1 : 0;
    for (int o = 32; o > 0; o >>= 1) cnt += __shfl_down(cnt, o, 64);
    __shared__ int s4[4];
    if ((threadIdx.x & 63) == 0) s4[threadIdx.x >> 6] = cnt;
    __syncthreads();
    if (threadIdx.x == 0) len[b] = s4[0] + s4[1] + s4[2] + s4[3];
}

// ---------------- sort by length (descending), group maxes ----------------
__global__ __launch_bounds__(256) void sort_k(const int* __restrict__ len,
                                              int* __restrict__ perm,
                                              int* __restrict__ glen)
{
    __shared__ int L[256];
    __shared__ int P[256];
    int tid = threadIdx.x;
    L[tid] = len[tid];
    __syncthreads();
    int l = L[tid], r = 0;
    for (int b = 0; b < 256; ++b) {
        int lb = L[b];
        r += (lb > l) || (lb == l && b < tid);
    }
    P[r] = tid;
    __syncthreads();
    perm[tid] = P[tid];
    if (tid < NG) glen[tid] = L[P[tid * SG]];
}

// ---------------- helpers ----------------
__device__ __forceinline__ void wait_flags(const int* __restrict__ flg, int target, int tid)
{
    int lane = tid & 63;
    while (true) {
        int v = target;
        if (lane < NJ)
            v = __hip_atomic_load(&flg[lane * FS], __ATOMIC_RELAXED, __HIP_MEMORY_SCOPE_AGENT);
        if (__all(v >= target)) break;
        __builtin_amdgcn_s_sleep(1);
    }
}

__device__ __forceinline__ void issue_pf(const float* __restrict__ hbuf, int g, int T,
                                         float (&pf)[8], int tid)
{
    const float* hsrc = hbuf + ((size_t)(T & 1) * BB + g * SG) * HH;
    int s = tid >> 6, l = tid & 63;
    const unsigned long long* p = (const unsigned long long*)(hsrc + (size_t)s * HH);
    #pragma unroll
    for (int q = 0; q < 4; ++q) {
        U64F v;
        v.u = __hip_atomic_load(&p[q * 64 + l], __ATOMIC_RELAXED, __HIP_MEMORY_SCOPE_AGENT);
        pf[2 * q]     = v.f[0];
        pf[2 * q + 1] = v.f[1];
    }
}

// One LSTM step for one group slice. pfCur holds h(t) (fp32, pairs by k).
// pfMode 1: mid-phase prefetch of pfN; pfMode 2: post-flag prefetch (solo tail).
__device__ __forceinline__ void do_phase(
    int g, int t, int tid, int jg,
    const float* __restrict__ traj, const int* __restrict__ osL,
    uint* __restrict__ hsL, float* __restrict__ carryL, float* __restrict__ gbL,
    float* __restrict__ xsL, float* __restrict__ mkL,
    const float* __restrict__ wih_s, const float* __restrict__ bsum_s,
    const uint (&w16)[64], float& creg,
    float (&pfCur)[8], float (&pfN)[8], int pfGrp, int pfT, int pfMode,
    float* __restrict__ hbuf, int* __restrict__ flags)
{
    const int rowq = tid >> 5, kc = tid & 31;
    const int swzd = (kc & 7) << 2;

    // stage h(t): fp32 regs -> packed half2 LDS (conflict-free writes)
    {
        int s = tid >> 6, l = tid & 63;
        #pragma unroll
        for (int q = 0; q < 4; ++q) {
            half2v h2;
            h2.x = (_Float16)pfCur[2 * q];
            h2.y = (_Float16)pfCur[2 * q + 1];
            int k2   = q * 64 + l;
            int cell = k2 >> 3, inner = k2 & 7;
            hsL[s * 256 + ((cell * 8 + inner) ^ ((cell & 7) << 2))] = pun(h2);
            // fp32 carry slice for this wg's j-range (masked carry-forward stays exact)
            if (q == (jg >> 2) && (l >> 4) == (jg & 3)) {
                carryL[s * 32 + 2 * (l & 15)]     = pfCur[2 * q];
                carryL[s * 32 + 2 * (l & 15) + 1] = pfCur[2 * q + 1];
            }
        }
    }
    if (tid < SG) {
        float v = traj[(size_t)osL[tid] * TT + t];
        xsL[tid] = v;
        mkL[tid] = (v != -1.0f) ? 1.f : 0.f;
    }
    __syncthreads();

    // matvec via v_dot2_f32_f16: 2 chunks of 4 samples
    #pragma unroll
    for (int cs = 0; cs < 2; ++cs) {
        float a[32];
        #pragma unroll
        for (int i = 0; i < 32; ++i) a[i] = 0.f;
        #pragma unroll
        for (int sp = 0; sp < 4; ++sp) {
            const int s = cs * 4 + sp;
            const int dwb = s * 256;
            uint4 r0 = *(const uint4*)&hsL[dwb + ((kc * 8 + 0) ^ swzd)];
            uint4 r1 = *(const uint4*)&hsL[dwb + ((kc * 8 + 4) ^ swzd)];
            uint h8[8] = {r0.x, r0.y, r0.z, r0.w, r1.x, r1.y, r1.z, r1.w};
            #pragma unroll
            for (int rr = 0; rr < 8; ++rr) {
                float acc = a[sp * 8 + rr];
                #pragma unroll
                for (int u = 0; u < 8; ++u)
                    acc = __builtin_amdgcn_fdot2(puh(w16[rr * 8 + u]), puh(h8[u]), acc, false);
                a[sp * 8 + rr] = acc;
            }
        }
        #pragma unroll
        for (int d = 0; d < 5; ++d) {
            const unsigned bsel = (kc >> d) & 1;
            #pragma unroll
            for (int j = 0; j < (16 >> d); ++j) {
                float v0 = a[2 * j], v1 = a[2 * j + 1];
                float send = bsel ? v0 : v1;
                float keep = bsel ? v1 : v0;
                float r = __shfl_xor(send, 1 << d, 64);
                a[j] = keep + r;
            }
        }
        {
            const int rloc = rowq * 8 + (kc & 7);
            const int sloc = cs * 4 + (kc >> 3);
            float pre = fmaf(xsL[sloc], wih_s[rloc], a[0] + bsum_s[rloc]);
            bool isg = ((rloc >> 5) == 2);
            float sc = isg ? 2.f : 1.f;
            float sg = 1.f / (1.f + __expf(-pre * sc));
            gbL[sloc * 136 + rloc] = fmaf(sg, sc, isg ? -1.f : 0.f);
        }
    }

    // mid-phase prefetch: hides LLC latency under update/store/flag/next staging
    if (pfMode == 1) {
        wait_flags(flags + pfGrp * NJ * FS, pfT, tid);
        issue_pf(hbuf, pfGrp, pfT, pfN, tid);
    }
    __syncthreads();

    // state update (c in register), store h(t+1) LLC-coherent
    if (tid < 256) {
        int s = tid >> 5, jj = tid & 31;
        float hv;
        if (mkL[s] > 0.f) {
            float iv = gbL[s * 136 + jj];
            float fv = gbL[s * 136 + 32 + jj];
            float gv = gbL[s * 136 + 64 + jj];
            float ov = gbL[s * 136 + 96 + jj];
            float cn = fmaf(fv, creg, iv * gv);
            creg = cn;
            float e = __expf(2.f * cn);
            hv = ov * (1.f - 2.f / (e + 1.f));
        } else {
            hv = carryL[s * 32 + jj];
        }
        float* hout = hbuf + ((size_t)((t + 1) & 1) * BB + g * SG) * HH;
        __hip_atomic_store(&hout[s * HH + jg * JW + jj], hv, __ATOMIC_RELAXED,
                           __HIP_MEMORY_SCOPE_AGENT);
    }
    __syncthreads();   // drains vmcnt: h stores visible before flag
    if (tid == 0)
        __hip_atomic_store(&flags[g * NJ * FS + jg * FS], t + 1, __ATOMIC_RELAXED,
                           __HIP_MEMORY_SCOPE_AGENT);
    if (pfMode == 2) {
        wait_flags(flags + pfGrp * NJ * FS, pfT, tid);
        issue_pf(hbuf, pfGrp, pfT, pfN, tid);
    }
}

// ---------------- persistent LSTM: fp16-dot2, reg-W, balanced pairs ----------
__global__ __launch_bounds__(512, 2) void lstm_persist(
    const float* __restrict__ traj, const float* __restrict__ Wih,
    const uint* __restrict__ Wpk16, const float* __restrict__ bsum,
    float* __restrict__ hbuf,                 // [2][BB][HH]
    const int* __restrict__ perm, const int* __restrict__ glen,
    int* __restrict__ flags)
{
    // one big genuinely-used LDS array (90KB) -> exactly 1 wg/CU
    __shared__ __align__(16) float smem[23040];
    __shared__ float xsm[2][SG], mkm[2][SG];
    __shared__ int   osm[2][SG];
    __shared__ float wih_s[RW], bsum_s[RW];

    uint*  const hsA16  = (uint*)(smem);          // 2048 dw
    uint*  const hsB16  = (uint*)(smem + 2048);   // 2048 dw
    float* const carryA = smem + 4096;            // 256
    float* const carryB = smem + 4352;            // 256
    float* const gbA    = smem + 4608;            // 1088
    float* const gbB    = smem + 5696;            // 1088

    const int wg  = blockIdx.x;
    const int p   = wg & 15;
    const int jg  = wg >> 4;
    const int tid = threadIdx.x;
    const int gA = p, gB = 31 - p;      // balanced pairing

    if (tid < 2 * SG) {
        int gi = tid >> 3, s = tid & 7;
        osm[gi][s] = perm[((gi == 0) ? gA : gB) * SG + s];
    }
    if (tid < RW) {
        int gate = tid >> 5, jj = tid & 31;
        int grow = gate * HH + jg * JW + jj;
        wih_s[tid]  = Wih[grow];
        bsum_s[tid] = bsum[grow];
    }
    const int glenA = glen[gA], glenB = glen[gB];   // glenA >= glenB

    // W slice (fp16 pairs) -> registers: 64 dwords
    uint w16[64];
    {
        const uint4* wp = (const uint4*)(Wpk16 + (size_t)(jg * 512 + tid) * 64);
        #pragma unroll
        for (int i = 0; i < 16; ++i) {
            uint4 v = wp[i];
            w16[4 * i] = v.x; w16[4 * i + 1] = v.y; w16[4 * i + 2] = v.z; w16[4 * i + 3] = v.w;
        }
    }

    float cA = 0.f, cB = 0.f;
    float pfA[8], pfB[8];
    #pragma unroll
    for (int q = 0; q < 8; ++q) { pfA[q] = 0.f; pfB[q] = 0.f; }   // h(0) = 0
    __syncthreads();

    for (int t = 0; t < glenA; ++t) {
        if (t < glenB) {
            do_phase(gA, t, tid, jg, traj, osm[0], hsA16, carryA, gbA, xsm[0], mkm[0],
                     wih_s, bsum_s, w16, cA, pfA, pfB, gB, t, 1, hbuf, flags);
            do_phase(gB, t, tid, jg, traj, osm[1], hsB16, carryB, gbB, xsm[1], mkm[1],
                     wih_s, bsum_s, w16, cB, pfB, pfA, gA, t + 1, 1, hbuf, flags);
        } else {
            do_phase(gA, t, tid, jg, traj, osm[0], hsA16, carryA, gbA, xsm[0], mkm[0],
                     wih_s, bsum_s, w16, cA, pfA, pfA, gA, t + 1,
                     (t + 1 < glenA) ? 2 : 0, hbuf, flags);
        }
    }
}

// ---------------- epilogue: logits + masked softmax ----------------
__global__ __launch_bounds__(256) void epi_k(
    const float* __restrict__ hbuf, const float* __restrict__ fcWT,
    const float* __restrict__ fcb, const int* __restrict__ len,
    const int* __restrict__ perm, const int* __restrict__ glen,
    float* __restrict__ out)
{
    __shared__ float hb[HH];
    __shared__ float lg[TT];
    __shared__ float red[4];
    const int slot = blockIdx.x, tid = threadIdx.x;
    const int ob = perm[slot];
    const int par = glen[slot >> 3] & 1;

    const float* hfin = hbuf + ((size_t)par * BB + slot) * HH;
    for (int i = tid; i < HH; i += 256) hb[i] = hfin[i];
    __syncthreads();

    const int t0 = tid * 4;
    float a0 = fcb[t0], a1 = fcb[t0 + 1], a2 = fcb[t0 + 2], a3 = fcb[t0 + 3];
    #pragma unroll 8
    for (int k = 0; k < HH; ++k) {
        float4 w = *(const float4*)&fcWT[k * TT + t0];
        float hv = hb[k];
        a0 += w.x * hv; a1 += w.y * hv; a2 += w.z * hv; a3 += w.w * hv;
    }
    lg[t0] = a0; lg[t0 + 1] = a1; lg[t0 + 2] = a2; lg[t0 + 3] = a3;
    __syncthreads();

    const int L = len[ob];
    float mx = -3.4e38f;
    for (int i = tid; i < L; i += 256) mx = fmaxf(mx, lg[i]);
    for (int o = 32; o > 0; o >>= 1) mx = fmaxf(mx, __shfl_down(mx, o, 64));
    if ((tid & 63) == 0) red[tid >> 6] = mx;
    __syncthreads();
    mx = fmaxf(fmaxf(red[0], red[1]), fmaxf(red[2], red[3]));
    __syncthreads();

    float sm = 0.f;
    for (int i = tid; i < L; i += 256) {
        float e = __expf(lg[i] - mx);
        lg[i] = e;
        sm += e;
    }
    for (int o = 32; o > 0; o >>= 1) sm += __shfl_down(sm, o, 64);
    if ((tid & 63) == 0) red[tid >> 6] = sm;
    __syncthreads();
    sm = red[0] + red[1] + red[2] + red[3];
    float inv = 1.f / sm;

    for (int i = tid; i < TT; i += 256)
        out[ob * TT + i] = (i < L) ? lg[i] * inv : 1.0f;
}

// ---------------- launch ----------------
extern "C" void kernel_launch(void* const* d_in, const int* in_sizes, int n_in,
                              void* d_out, int out_size, void* d_ws, size_t ws_size,
                              hipStream_t stream)
{
    const float* traj = (const float*)d_in[0];
    const float* Wih  = (const float*)d_in[1];
    const float* Whh  = (const float*)d_in[2];
    const float* bih  = (const float*)d_in[3];
    const float* bhh  = (const float*)d_in[4];
    const float* fcW  = (const float*)d_in[5];
    const float* fcb  = (const float*)d_in[6];
    float* out = (float*)d_out;

    uint*  Wpk16 = (uint*)d_ws;                 // 524,288 dw (2MB)
    float* fcWT  = (float*)(Wpk16 + NJ * 512 * 64);  // 524,288
    float* bsum  = fcWT + HH * TT;              // 2,048
    float* hbuf  = bsum + G4;                   // 2 * 131,072
    int*   len   = (int*)(hbuf + 2 * BB * HH);  // 256
    int*   perm  = len + BB;                    // 256
    int*   glen  = perm + BB;                   // 32
    int*   flags = glen + NG;                   // 32*16*32

    prep_k<<<2048, 256, 0, stream>>>(Whh, fcW, bih, bhh, Wpk16, fcWT, bsum, hbuf, flags);
    lens_k<<<BB, 256, 0, stream>>>(traj, len);
    sort_k<<<1, 256, 0, stream>>>(len, perm, glen);

    {
        const float* traj_l = traj; const float* wih_l = Wih;
        const uint* wpk_l = Wpk16;  const float* bsum_l = bsum;
        float* hbuf_l = hbuf;
        const int* perm_l = perm;   const int* glen_l = glen;
        int* flags_l = flags;
        void* args[] = { (void*)&traj_l, (void*)&wih_l, (void*)&wpk_l, (void*)&bsum_l,
                         (void*)&hbuf_l, (void*)&perm_l, (void*)&glen_l, (void*)&flags_l };
        hipLaunchCooperativeKernel((const void*)lstm_persist, dim3(256), dim3(512),
                                   args, 0, stream);
    }

    epi_k<<<BB, 256, 0, stream>>>(hbuf, fcWT, fcb, len, perm, glen, out);
}

// Round 8
// 2494.377 us; speedup vs baseline: 15.4287x; 2.2958x over previous
//
#include <hip/hip_runtime.h>

#define TT 1024
#define BB 256
#define HH 512
#define G4 2048
#define NG 32   // sample groups
#define SG 8    // samples per group
#define NJ 16   // wgs (j-slices) per group
#define RW 128  // rows per slice = 4 gates * 32 j
#define JW 32   // j per slice
#define FS 32   // flag stride (ints)

typedef _Float16 half2v __attribute__((ext_vector_type(2)));
typedef _Float16 half8  __attribute__((ext_vector_type(8)));
typedef __fp16   fp16x2 __attribute__((ext_vector_type(2)));
typedef float    f32x4  __attribute__((ext_vector_type(4)));
typedef unsigned int uint;

union U32H  { uint u; half2v h; fp16x2 g; };
union U128H { uint4 u; half8 h; };
union U64F  { unsigned long long u; float f[2]; };

// ---------------- prep: fp16 W repack into MFMA A-fragments ----------------
// idx = (((jg*8 + w)*16 + kk)*64 + l)*4 + d :
//   A-frag for wave w of slice jg, K-step kk: lane l supplies
//   A[m = l&15][k = kk*32 + (l>>4)*8 + 2d (+1)] ; row rl = w*16 + (l&15),
//   gate = rl>>5, jj = rl&31, grow = gate*512 + jg*32 + jj.
__global__ __launch_bounds__(256) void prep_k(
    const float* __restrict__ Whh, const float* __restrict__ fcW,
    const float* __restrict__ bih, const float* __restrict__ bhh,
    uint* __restrict__ Wpk16, float* __restrict__ fcWT, float* __restrict__ bsum,
    float* __restrict__ hbuf, int* __restrict__ flags)
{
    int n  = blockDim.x * gridDim.x;
    int i0 = blockIdx.x * blockDim.x + threadIdx.x;
    for (int i = i0; i < NJ * 8 * 16 * 64 * 4; i += n) {
        int d  = i & 3;
        int l  = (i >> 2) & 63;
        int kk = (i >> 8) & 15;
        int w  = (i >> 12) & 7;
        int jg = (i >> 15) & 15;
        int rl   = w * 16 + (l & 15);
        int gate = rl >> 5, jj = rl & 31;
        int grow = gate * HH + jg * JW + jj;
        int k    = kk * 32 + ((l >> 4) & 3) * 8 + 2 * d;
        half2v p;
        p.x = (_Float16)Whh[grow * HH + k];
        p.y = (_Float16)Whh[grow * HH + k + 1];
        U32H x; x.h = p;
        Wpk16[i] = x.u;
    }
    for (int i = i0; i < HH * TT; i += n) {
        int k = i >> 10, t = i & (TT - 1);
        fcWT[i] = fcW[t * HH + k];
    }
    for (int i = i0; i < G4; i += n) bsum[i] = bih[i] + bhh[i];
    for (int i = i0; i < 2 * BB * HH; i += n) hbuf[i] = 0.f;
    for (int i = i0; i < NG * NJ * FS; i += n) flags[i] = 0;
}

// ---------------- lengths ----------------
__global__ __launch_bounds__(256) void lens_k(const float* __restrict__ traj,
                                              int* __restrict__ len)
{
    int b = blockIdx.x;
    int cnt = 0;
    for (int i = threadIdx.x; i < TT; i += 256)
        cnt += (traj[b * TT + i] != -1.0f) ? 1 : 0;
    for (int o = 32; o > 0; o >>= 1) cnt += __shfl_down(cnt, o, 64);
    __shared__ int s4[4];
    if ((threadIdx.x & 63) == 0) s4[threadIdx.x >> 6] = cnt;
    __syncthreads();
    if (threadIdx.x == 0) len[b] = s4[0] + s4[1] + s4[2] + s4[3];
}

// ---------------- sort by length (descending), group maxes ----------------
__global__ __launch_bounds__(256) void sort_k(const int* __restrict__ len,
                                              int* __restrict__ perm,
                                              int* __restrict__ glen)
{
    __shared__ int L[256];
    __shared__ int P[256];
    int tid = threadIdx.x;
    L[tid] = len[tid];
    __syncthreads();
    int l = L[tid], r = 0;
    for (int b = 0; b < 256; ++b) {
        int lb = L[b];
        r += (lb > l) || (lb == l && b < tid);
    }
    P[r] = tid;
    __syncthreads();
    perm[tid] = P[tid];
    if (tid < NG) glen[tid] = L[P[tid * SG]];
}

// ---------------- helpers ----------------
__device__ __forceinline__ void wait_flags(const int* __restrict__ flg, int target, int tid)
{
    int lane = tid & 63;
    while (true) {
        int v = target;
        if (lane < NJ)
            v = __hip_atomic_load(&flg[lane * FS], __ATOMIC_RELAXED, __HIP_MEMORY_SCOPE_AGENT);
        if (__all(v >= target)) break;
        __builtin_amdgcn_s_sleep(1);
    }
}

__device__ __forceinline__ void issue_pf(const float* __restrict__ hbuf, int g, int T,
                                         float (&pf)[8], int tid)
{
    const float* hsrc = hbuf + ((size_t)(T & 1) * BB + g * SG) * HH;
    int s = tid >> 6, l = tid & 63;
    const unsigned long long* p = (const unsigned long long*)(hsrc + (size_t)s * HH);
    #pragma unroll
    for (int q = 0; q < 4; ++q) {
        U64F v;
        v.u = __hip_atomic_load(&p[q * 64 + l], __ATOMIC_RELAXED, __HIP_MEMORY_SCOPE_AGENT);
        pf[2 * q]     = v.f[0];
        pf[2 * q + 1] = v.f[1];
    }
}

// One LSTM step for one group slice, MFMA matvec.
// pfMode 1: mid-phase prefetch of pfN; pfMode 2: post-flag prefetch (solo tail).
__device__ __forceinline__ void do_phase(
    int g, int t, int tid, int jg,
    const float* __restrict__ traj, const int* __restrict__ osL,
    uint* __restrict__ hsL, float* __restrict__ carryL, float* __restrict__ gbL,
    float* __restrict__ xsL, float* __restrict__ mkL,
    const float* __restrict__ wih_s, const float* __restrict__ bsum_s,
    const half8 (&wf)[16], float& creg,
    float (&pfCur)[8], float (&pfN)[8], int pfGrp, int pfT, int pfMode,
    float* __restrict__ hbuf, int* __restrict__ flags)
{
    const int w  = tid >> 6;         // wave id: owns rows w*16..w*16+15
    const int l  = tid & 63;
    const int sm = l & 15;           // MFMA n-index (sample; 8..15 discarded)
    const int ks = (l >> 4) & 3;     // k-subgroup

    // stage h(t): fp32 regs -> packed half2 LDS (swizzled), + fp32 carry slice
    {
        int s = w;                   // wave id doubles as sample id for staging
        int swz = (s & 7) << 2;
        #pragma unroll
        for (int q = 0; q < 4; ++q) {
            U32H x;
            x.g = __builtin_amdgcn_cvt_pkrtz(pfCur[2 * q], pfCur[2 * q + 1]);
            int k2 = q * 64 + l;
            hsL[s * 256 + (k2 ^ swz)] = x.u;
            if (q == (jg >> 2) && (l >> 4) == (jg & 3)) {
                carryL[s * 32 + 2 * (l & 15)]     = pfCur[2 * q];
                carryL[s * 32 + 2 * (l & 15) + 1] = pfCur[2 * q + 1];
            }
        }
    }
    if (tid < SG) {
        float v = traj[(size_t)osL[tid] * TT + t];
        xsL[tid] = v;
        mkL[tid] = (v != -1.0f) ? 1.f : 0.f;
    }
    __syncthreads();

    // MFMA matvec: D[16 rows x 16 samples], K = 512 in 16 steps, 2 acc chains
    f32x4 acc0 = {0.f, 0.f, 0.f, 0.f}, acc1 = {0.f, 0.f, 0.f, 0.f};
    {
        const int smswz = (sm & 7) << 2;
        const int bbase = sm * 256;
        #pragma unroll
        for (int kk = 0; kk < 16; kk += 2) {
            U128H b0, b1;
            b0.u = *(const uint4*)&hsL[bbase + ((kk * 16 + ks * 4) ^ smswz)];
            b1.u = *(const uint4*)&hsL[bbase + (((kk + 1) * 16 + ks * 4) ^ smswz)];
            acc0 = __builtin_amdgcn_mfma_f32_16x16x32_f16(wf[kk],     b0.h, acc0, 0, 0, 0);
            acc1 = __builtin_amdgcn_mfma_f32_16x16x32_f16(wf[kk + 1], b1.h, acc1, 0, 0, 0);
        }
    }

    // gates: lane holds 4 rows (m = ks*4+r) for sample sm
    if (sm < SG) {
        float xv = xsL[sm];
        #pragma unroll
        for (int r = 0; r < 4; ++r) {
            int rl = w * 16 + ks * 4 + r;
            float pre = fmaf(xv, wih_s[rl], (acc0[r] + acc1[r]) + bsum_s[rl]);
            bool isg = ((rl >> 5) == 2);
            float sc = isg ? 2.f : 1.f;
            float sg = 1.f / (1.f + __expf(-pre * sc));
            gbL[sm * 136 + rl] = fmaf(sg, sc, isg ? -1.f : 0.f);
        }
    }

    // mid-phase prefetch: hides LLC latency under update/store/flag/next staging
    if (pfMode == 1) {
        wait_flags(flags + pfGrp * NJ * FS, pfT, tid);
        issue_pf(hbuf, pfGrp, pfT, pfN, tid);
    }
    __syncthreads();

    // state update (c in register), store h(t+1) LLC-coherent
    if (tid < 256) {
        int s = tid >> 5, jj = tid & 31;
        float hv;
        if (mkL[s] > 0.f) {
            float iv = gbL[s * 136 + jj];
            float fv = gbL[s * 136 + 32 + jj];
            float gv = gbL[s * 136 + 64 + jj];
            float ov = gbL[s * 136 + 96 + jj];
            float cn = fmaf(fv, creg, iv * gv);
            creg = cn;
            float e = __expf(2.f * cn);
            hv = ov * (1.f - 2.f / (e + 1.f));
        } else {
            hv = carryL[s * 32 + jj];
        }
        float* hout = hbuf + ((size_t)((t + 1) & 1) * BB + g * SG) * HH;
        __hip_atomic_store(&hout[s * HH + jg * JW + jj], hv, __ATOMIC_RELAXED,
                           __HIP_MEMORY_SCOPE_AGENT);
    }
    __syncthreads();   // drains vmcnt: h stores visible before flag
    if (tid == 0)
        __hip_atomic_store(&flags[g * NJ * FS + jg * FS], t + 1, __ATOMIC_RELAXED,
                           __HIP_MEMORY_SCOPE_AGENT);
    if (pfMode == 2) {
        wait_flags(flags + pfGrp * NJ * FS, pfT, tid);
        issue_pf(hbuf, pfGrp, pfT, pfN, tid);
    }
}

// ---------------- persistent LSTM: MFMA, reg-W fragments, balanced pairs ----
__global__ __launch_bounds__(512, 2) void lstm_persist(
    const float* __restrict__ traj, const float* __restrict__ Wih,
    const uint* __restrict__ Wpk16, const float* __restrict__ bsum,
    float* __restrict__ hbuf,                 // [2][BB][HH]
    const int* __restrict__ perm, const int* __restrict__ glen,
    int* __restrict__ flags)
{
    // one big genuinely-used LDS array (90KB) -> exactly 1 wg/CU
    __shared__ __align__(16) float smem[23040];
    __shared__ float xsm[2][SG], mkm[2][SG];
    __shared__ int   osm[2][SG];
    __shared__ float wih_s[RW], bsum_s[RW];

    uint*  const hsA16  = (uint*)smem;            // 4096 dw (16 samples x 256)
    uint*  const hsB16  = (uint*)(smem + 4096);   // 4096 dw
    float* const carryA = smem + 8192;            // 256
    float* const carryB = smem + 8448;            // 256
    float* const gbA    = smem + 8704;            // 1088
    float* const gbB    = smem + 9792;            // 1088

    const int wg  = blockIdx.x;
    const int p   = wg & 15;
    const int jg  = wg >> 4;
    const int tid = threadIdx.x;
    const int gA = p, gB = 31 - p;      // balanced pairing

    if (tid < 2 * SG) {
        int gi = tid >> 3, s = tid & 7;
        osm[gi][s] = perm[((gi == 0) ? gA : gB) * SG + s];
    }
    if (tid < RW) {
        int gate = tid >> 5, jj = tid & 31;
        int grow = gate * HH + jg * JW + jj;
        wih_s[tid]  = Wih[grow];
        bsum_s[tid] = bsum[grow];
    }
    const int glenA = glen[gA], glenB = glen[gB];   // glenA >= glenB

    // W A-fragments -> registers: 16 x half8 (64 VGPRs), coalesced per kk
    half8 wf[16];
    {
        const int w = tid >> 6, l = tid & 63;
        const uint4* wp = (const uint4*)Wpk16;
        const int base = (jg * 8 + w) * 1024 + l;   // ((jg*8+w)*16 + kk)*64 + l
        #pragma unroll
        for (int kk = 0; kk < 16; ++kk) {
            U128H u; u.u = wp[base + kk * 64];
            wf[kk] = u.h;
        }
    }

    float cA = 0.f, cB = 0.f;
    float pfA[8], pfB[8];
    #pragma unroll
    for (int q = 0; q < 8; ++q) { pfA[q] = 0.f; pfB[q] = 0.f; }   // h(0) = 0
    __syncthreads();

    for (int t = 0; t < glenA; ++t) {
        if (t < glenB) {
            do_phase(gA, t, tid, jg, traj, osm[0], hsA16, carryA, gbA, xsm[0], mkm[0],
                     wih_s, bsum_s, wf, cA, pfA, pfB, gB, t, 1, hbuf, flags);
            do_phase(gB, t, tid, jg, traj, osm[1], hsB16, carryB, gbB, xsm[1], mkm[1],
                     wih_s, bsum_s, wf, cB, pfB, pfA, gA, t + 1, 1, hbuf, flags);
        } else {
            do_phase(gA, t, tid, jg, traj, osm[0], hsA16, carryA, gbA, xsm[0], mkm[0],
                     wih_s, bsum_s, wf, cA, pfA, pfA, gA, t + 1,
                     (t + 1 < glenA) ? 2 : 0, hbuf, flags);
        }
    }
}

// ---------------- epilogue: logits + masked softmax ----------------
__global__ __launch_bounds__(256) void epi_k(
    const float* __restrict__ hbuf, const float* __restrict__ fcWT,
    const float* __restrict__ fcb, const int* __restrict__ len,
    const int* __restrict__ perm, const int* __restrict__ glen,
    float* __restrict__ out)
{
    __shared__ float hb[HH];
    __shared__ float lg[TT];
    __shared__ float red[4];
    const int slot = blockIdx.x, tid = threadIdx.x;
    const int ob = perm[slot];
    const int par = glen[slot >> 3] & 1;

    const float* hfin = hbuf + ((size_t)par * BB + slot) * HH;
    for (int i = tid; i < HH; i += 256) hb[i] = hfin[i];
    __syncthreads();

    const int t0 = tid * 4;
    float a0 = fcb[t0], a1 = fcb[t0 + 1], a2 = fcb[t0 + 2], a3 = fcb[t0 + 3];
    #pragma unroll 8
    for (int k = 0; k < HH; ++k) {
        float4 w = *(const float4*)&fcWT[k * TT + t0];
        float hv = hb[k];
        a0 += w.x * hv; a1 += w.y * hv; a2 += w.z * hv; a3 += w.w * hv;
    }
    lg[t0] = a0; lg[t0 + 1] = a1; lg[t0 + 2] = a2; lg[t0 + 3] = a3;
    __syncthreads();

    const int L = len[ob];
    float mx = -3.4e38f;
    for (int i = tid; i < L; i += 256) mx = fmaxf(mx, lg[i]);
    for (int o = 32; o > 0; o >>= 1) mx = fmaxf(mx, __shfl_down(mx, o, 64));
    if ((tid & 63) == 0) red[tid >> 6] = mx;
    __syncthreads();
    mx = fmaxf(fmaxf(red[0], red[1]), fmaxf(red[2], red[3]));
    __syncthreads();

    float sm = 0.f;
    for (int i = tid; i < L; i += 256) {
        float e = __expf(lg[i] - mx);
        lg[i] = e;
        sm += e;
    }
    for (int o = 32; o > 0; o >>= 1) sm += __shfl_down(sm, o, 64);
    if ((tid & 63) == 0) red[tid >> 6] = sm;
    __syncthreads();
    sm = red[0] + red[1] + red[2] + red[3];
    float inv = 1.f / sm;

    for (int i = tid; i < TT; i += 256)
        out[ob * TT + i] = (i < L) ? lg[i] * inv : 1.0f;
}

// ---------------- launch ----------------
extern "C" void kernel_launch(void* const* d_in, const int* in_sizes, int n_in,
                              void* d_out, int out_size, void* d_ws, size_t ws_size,
                              hipStream_t stream)
{
    const float* traj = (const float*)d_in[0];
    const float* Wih  = (const float*)d_in[1];
    const float* Whh  = (const float*)d_in[2];
    const float* bih  = (const float*)d_in[3];
    const float* bhh  = (const float*)d_in[4];
    const float* fcW  = (const float*)d_in[5];
    const float* fcb  = (const float*)d_in[6];
    float* out = (float*)d_out;

    uint*  Wpk16 = (uint*)d_ws;                      // 524,288 dw (2MB)
    float* fcWT  = (float*)(Wpk16 + NJ * 8 * 16 * 64 * 4);  // 524,288
    float* bsum  = fcWT + HH * TT;                   // 2,048
    float* hbuf  = bsum + G4;                        // 2 * 131,072
    int*   len   = (int*)(hbuf + 2 * BB * HH);       // 256
    int*   perm  = len + BB;                         // 256
    int*   glen  = perm + BB;                        // 32
    int*   flags = glen + NG;                        // 32*16*32

    prep_k<<<2048, 256, 0, stream>>>(Whh, fcW, bih, bhh, Wpk16, fcWT, bsum, hbuf, flags);
    lens_k<<<BB, 256, 0, stream>>>(traj, len);
    sort_k<<<1, 256, 0, stream>>>(len, perm, glen);

    {
        const float* traj_l = traj; const float* wih_l = Wih;
        const uint* wpk_l = Wpk16;  const float* bsum_l = bsum;
        float* hbuf_l = hbuf;
        const int* perm_l = perm;   const int* glen_l = glen;
        int* flags_l = flags;
        void* args[] = { (void*)&traj_l, (void*)&wih_l, (void*)&wpk_l, (void*)&bsum_l,
                         (void*)&hbuf_l, (void*)&perm_l, (void*)&glen_l, (void*)&flags_l };
        (void)hipLaunchCooperativeKernel((const void*)lstm_persist, dim3(256), dim3(512),
                                         args, 0, stream);
    }

    epi_k<<<BB, 256, 0, stream>>>(hbuf, fcWT, fcb, len, perm, glen, out);
}